// Round 3
// baseline (937.231 us; speedup 1.0000x reference)
//
#include <hip/hip_runtime.h>
#include <hip/hip_bf16.h>
#include <stdint.h>

// LSTM-CRF forward loss. B=128 L=256 V=6000 E=128 RV=300 RD=100 H=256 C=33
// DIN=428 (pad to 448). Pipeline:
//   pack_weights (Wih bf16, Whh fp8-frag, bias, Wcls) -> pack_A -> gemm_xg
//   -> lstm_recur (16 wg; Whh split 64VGPR-regs + 128KB LDS; h fp8 LDS dbuf)
//   -> emis_k -> golden_k -> crf_k -> fin_k

typedef unsigned short u16;
typedef __attribute__((ext_vector_type(8))) __bf16 bf16x8;
typedef __attribute__((ext_vector_type(4))) float f32x4;

struct __align__(8) u16x4 { u16 x, y, z, w; };

typedef const void __attribute__((address_space(1))) gas_t;
typedef void __attribute__((address_space(3))) las_t;

static __device__ __forceinline__ void gload16(const void* g, void* l) {
  __builtin_amdgcn_global_load_lds((gas_t*)g, (las_t*)l, 16, 0, 0);
}

static __device__ __forceinline__ u16 f2b(float x) {
  uint32_t u = __builtin_bit_cast(uint32_t, x);
  uint32_t r = u + 0x7fffu + ((u >> 16) & 1u);
  return (u16)(r >> 16);
}
static __device__ __forceinline__ float b2f(u16 u) {
  return __builtin_bit_cast(float, ((uint32_t)u) << 16);
}
static __device__ __forceinline__ float b2fu(unsigned int u) {
  return __builtin_bit_cast(float, u << 16);
}
static __device__ __forceinline__ float sigf(float x) {
  return __builtin_amdgcn_rcpf(1.f + __expf(-x));
}
static __device__ __forceinline__ float tanh_(float x) {
  return 1.f - 2.f * __builtin_amdgcn_rcpf(1.f + __expf(2.f * x));
}
static __device__ __forceinline__ f32x4 MFMA(bf16x8 a, bf16x8 b, f32x4 c) {
  return __builtin_amdgcn_mfma_f32_16x16x32_bf16(a, b, c, 0, 0, 0);
}

// ---------------- pack weights ----------------
// WihP[2048][448] bf16; bias[2048] f32 = bih+bhh; WclsP[48][512] bf16;
// WhhF8: fp8 e4m3 B-fragments, long-index ((d*8+v)*64 + (gate*2+jf)*8+kf)*64 + lane,
//   byte e: source Whh_d[row = gate*256+v*32+jf*16+(lane&15)][k = kf*32+(lane>>4)*8+e]
__global__ __launch_bounds__(256) void pack_weights(
    const float* __restrict__ Wih_f, const float* __restrict__ Wih_b,
    const float* __restrict__ Whh_f, const float* __restrict__ Whh_b,
    const float* __restrict__ bih_f, const float* __restrict__ bhh_f,
    const float* __restrict__ bih_b, const float* __restrict__ bhh_b,
    const float* __restrict__ Wcls,
    u16* __restrict__ WihP, unsigned int* __restrict__ WhhF8,
    float* __restrict__ biasP, u16* __restrict__ WclsP) {
  int idx = blockIdx.x * 256 + threadIdx.x;
  if (idx < 917504) {                       // 2*1024*448
    int d = idx / 458752;
    int rem = idx - d * 458752;
    int r = rem / 448, k = rem - r * 448;
    const float* W = d ? Wih_b : Wih_f;
    WihP[idx] = (k < 428) ? f2b(W[r * 428 + k]) : (u16)0;
  } else if (idx < 919552) {                // bias 2048
    int j = idx - 917504;
    int r = j & 1023;
    biasP[j] = (j >> 10) ? (bih_b[r] + bhh_b[r]) : (bih_f[r] + bhh_f[r]);
  } else if (idx < 944128) {                // Wcls 48*512
    int j = idx - 919552;
    int r = j >> 9, k = j & 511;
    WclsP[j] = (r < 33) ? f2b(Wcls[r * 512 + k]) : (u16)0;
  } else if (idx < 1075200) {               // WhhF8: 131072 dwords
    int q = idx - 944128;
    int eh = q & 1, li = (q >> 1) & 63, fi = (q >> 7) & 63;
    int v = (q >> 13) & 7, dd = q >> 16;
    int l16 = li & 15, g = li >> 4;
    int kf = fi & 7, gj = fi >> 3;
    int gate = gj >> 1, jf = gj & 1;
    int row = gate * 256 + v * 32 + jf * 16 + l16;
    int col = kf * 32 + g * 8 + eh * 4;
    const float* W = dd ? Whh_b : Whh_f;
    float4 f = *(const float4*)(W + (size_t)row * 256 + col);
    unsigned int r01 = __builtin_amdgcn_cvt_pk_fp8_f32(f.x, f.y, 0u, false) & 0xffffu;
    unsigned int r23 = __builtin_amdgcn_cvt_pk_fp8_f32(f.z, f.w, 0u, false) & 0xffffu;
    WhhF8[q] = r01 | (r23 << 16);
  }
}

// ---------------- gather + pack A: [32768][448] bf16 ----------------
__global__ __launch_bounds__(256) void pack_A(const int* __restrict__ data,
    const int* __restrict__ onerad, const float* __restrict__ embed,
    const float* __restrict__ rad, u16* __restrict__ A) {
  int idx = blockIdx.x * 256 + threadIdx.x;
  int m = idx / 112;
  int c = idx - m * 112;
  int k0 = c * 4;
  float4 vv;
  if (k0 < 128)      vv = *(const float4*)(embed + (size_t)data[m] * 128 + k0);
  else if (k0 < 228) vv = *(const float4*)(rad + (size_t)onerad[m] * 100 + (k0 - 128));
  else if (k0 < 328) vv = *(const float4*)(rad + (size_t)onerad[32768 + m] * 100 + (k0 - 228));
  else if (k0 < 428) vv = *(const float4*)(rad + (size_t)onerad[65536 + m] * 100 + (k0 - 328));
  else               vv = make_float4(0.f, 0.f, 0.f, 0.f);
  u16x4 o4 = { f2b(vv.x), f2b(vv.y), f2b(vv.z), f2b(vv.w) };
  *(u16x4*)(A + (size_t)m * 448 + k0) = o4;
}

// ---------------- xg GEMM: C[32768][2048] bf16 = A @ Wih^T + bias ----------------
__global__ __launch_bounds__(256) void gemm_xg(const u16* __restrict__ A,
    const u16* __restrict__ Bw, const float* __restrict__ bias,
    u16* __restrict__ Cout) {
  __shared__ u16 As[4096];
  __shared__ u16 Bs[4096];
  int bid = blockIdx.x;
  int mt = bid >> 4, nt = bid & 15;
  int m0 = mt * 128, n0 = nt * 128;
  int tid = threadIdx.x;
  int w = tid >> 6, lane = tid & 63, l16 = lane & 15, g = lane >> 4;
  int wr = w >> 1, wc = w & 1;
  int srow = tid >> 2, sch = tid & 3;
  f32x4 zero4 = {0.f, 0.f, 0.f, 0.f};
  f32x4 acc[4][4];
#pragma unroll
  for (int i = 0; i < 4; ++i)
#pragma unroll
    for (int j = 0; j < 4; ++j) acc[i][j] = zero4;
  for (int kk = 0; kk < 14; ++kk) {
    int kb = kk * 32;
    gload16(A + (size_t)(m0 + srow) * 448 + kb + sch * 8, (char*)As + tid * 16);
    gload16(A + (size_t)(m0 + srow + 64) * 448 + kb + sch * 8, (char*)As + 4096 + tid * 16);
    gload16(Bw + (size_t)(n0 + srow) * 448 + kb + sch * 8, (char*)Bs + tid * 16);
    gload16(Bw + (size_t)(n0 + srow + 64) * 448 + kb + sch * 8, (char*)Bs + 4096 + tid * 16);
    __syncthreads();
    bf16x8 af[4], bfr[4];
#pragma unroll
    for (int i = 0; i < 4; ++i) {
      af[i]  = *(const bf16x8*)((const char*)As + (wr * 64 + i * 16 + l16) * 64 + g * 16);
      bfr[i] = *(const bf16x8*)((const char*)Bs + (wc * 64 + i * 16 + l16) * 64 + g * 16);
    }
#pragma unroll
    for (int i = 0; i < 4; ++i)
#pragma unroll
      for (int j = 0; j < 4; ++j)
        acc[i][j] = MFMA(af[i], bfr[j], acc[i][j]);
    __syncthreads();
  }
  float bv[4];
#pragma unroll
  for (int j = 0; j < 4; ++j) bv[j] = bias[n0 + wc * 64 + j * 16 + l16];
#pragma unroll
  for (int i = 0; i < 4; ++i)
#pragma unroll
    for (int j = 0; j < 4; ++j) {
      int col = n0 + wc * 64 + j * 16 + l16;
#pragma unroll
      for (int r = 0; r < 4; ++r) {
        int row = m0 + wr * 64 + i * 16 + g * 4 + r;
        Cout[(size_t)row * 2048 + col] = f2b(acc[i][j][r] + bv[j]);
      }
    }
}

// ---------------- LSTM recurrence, Whh resident: 64 VGPR + 128KB LDS ----------------
// 16 blocks x 512 thr, dynamic smem 139264 B:
//   [0,131072)        WhhLds: fp8 B-frags kf in [4,8), long-idx v*2048+(gj*4+kf-4)*64+lane
//   [131072,139264)   hfrag[2][4096]: h_{t-1} fp8 A-frags, double-buffered
// breg[32] (64 VGPR): kf in [0,4). One barrier/step; xg reg-prefetched 1 step ahead.
__global__ __launch_bounds__(512, 2) void lstm_recur(const u16* __restrict__ xg,
    const unsigned char* __restrict__ WhhF8, u16* __restrict__ outh) {
  extern __shared__ char smem[];
  long* WhhLds = (long*)smem;
  unsigned char* hfrag0 = (unsigned char*)(smem + 131072);
  int blk = blockIdx.x;
  int d = blk >> 3, ch = blk & 7, b0 = ch * 16;
  int tid = threadIdx.x;
  int v = tid >> 6, lane = tid & 63, l16 = lane & 15, g = lane >> 4;

  const long* Wl = (const long*)WhhF8 + (size_t)(d * 8 + v) * 4096;
  // registers: kf 0..3
  long breg[32];
#pragma unroll
  for (int gj = 0; gj < 8; ++gj)
#pragma unroll
    for (int kf = 0; kf < 4; ++kf)
      breg[gj * 4 + kf] = Wl[(gj * 8 + kf) * 64 + lane];
  // LDS: kf 4..7
#pragma unroll
  for (int gj = 0; gj < 8; ++gj)
#pragma unroll
    for (int k2 = 0; k2 < 4; ++k2)
      WhhLds[v * 2048 + (gj * 4 + k2) * 64 + lane] = Wl[(gj * 8 + 4 + k2) * 64 + lane];
  for (int i = tid; i < 2048; i += 512) ((int*)hfrag0)[i] = 0;

  // xg prefetch pointers: 4 batch rows, 8 values each via imm offsets
  int t0 = d ? 255 : 0;
  const u16* xr0 = xg + (size_t)((b0 + g * 4 + 0) * 256 + t0) * 2048 + d * 1024 + v * 32 + l16;
  const u16* xr1 = xg + (size_t)((b0 + g * 4 + 1) * 256 + t0) * 2048 + d * 1024 + v * 32 + l16;
  const u16* xr2 = xg + (size_t)((b0 + g * 4 + 2) * 256 + t0) * 2048 + d * 1024 + v * 32 + l16;
  const u16* xr3 = xg + (size_t)((b0 + g * 4 + 3) * 256 + t0) * 2048 + d * 1024 + v * 32 + l16;
  int tstep = d ? -2048 : 2048;

  unsigned int px[32];
#pragma unroll
  for (int gate = 0; gate < 4; ++gate)
#pragma unroll
    for (int jf = 0; jf < 2; ++jf) {
      px[0 * 8 + gate * 2 + jf] = xr0[gate * 256 + jf * 16];
      px[1 * 8 + gate * 2 + jf] = xr1[gate * 256 + jf * 16];
      px[2 * 8 + gate * 2 + jf] = xr2[gate * 256 + jf * 16];
      px[3 * 8 + gate * 2 + jf] = xr3[gate * 256 + jf * 16];
    }

  f32x4 zero4 = {0.f, 0.f, 0.f, 0.f};
  f32x4 cst[2] = {zero4, zero4};
  size_t obase = (size_t)((b0 + g * 4) * 256) * 512 + d * 256 + v * 32 + l16;
  const long* wl = WhhLds + v * 2048 + lane;
  __syncthreads();

#pragma unroll 1
  for (int tt = 0; tt < 256; ++tt) {
    int t = d ? (255 - tt) : tt;
    int p = tt & 1;
    // 1. acc init = xg (bias folded)
    f32x4 acc[4][2];
#pragma unroll
    for (int gate = 0; gate < 4; ++gate)
#pragma unroll
      for (int jf = 0; jf < 2; ++jf)
#pragma unroll
        for (int r = 0; r < 4; ++r)
          acc[gate][jf][r] = b2fu(px[r * 8 + gate * 2 + jf]);
    // 2. prefetch next step (benign in-workspace OOB at the final step)
    xr0 += tstep; xr1 += tstep; xr2 += tstep; xr3 += tstep;
#pragma unroll
    for (int gate = 0; gate < 4; ++gate)
#pragma unroll
      for (int jf = 0; jf < 2; ++jf) {
        px[0 * 8 + gate * 2 + jf] = xr0[gate * 256 + jf * 16];
        px[1 * 8 + gate * 2 + jf] = xr1[gate * 256 + jf * 16];
        px[2 * 8 + gate * 2 + jf] = xr2[gate * 256 + jf * 16];
        px[3 * 8 + gate * 2 + jf] = xr3[gate * 256 + jf * 16];
      }
    // 3. gates += h_{t-1} @ Whh^T  (fp8 MFMA; B kf<4 from regs, kf>=4 from LDS)
    {
      const long* fr = (const long*)(hfrag0 + p * 4096);
#pragma unroll
      for (int kf = 0; kf < 4; ++kf) {
        long a = fr[kf * 64 + lane];
#pragma unroll
        for (int gj = 0; gj < 8; ++gj)
          acc[gj >> 1][gj & 1] = __builtin_amdgcn_mfma_f32_16x16x32_fp8_fp8(
              a, breg[gj * 4 + kf], acc[gj >> 1][gj & 1], 0, 0, 0);
      }
#pragma unroll
      for (int kf = 0; kf < 4; ++kf) {
        long a = fr[(4 + kf) * 64 + lane];
#pragma unroll
        for (int gj = 0; gj < 8; ++gj)
          acc[gj >> 1][gj & 1] = __builtin_amdgcn_mfma_f32_16x16x32_fp8_fp8(
              a, wl[(gj * 4 + kf) * 64], acc[gj >> 1][gj & 1], 0, 0, 0);
      }
    }
    // 4. activations; write h (fp8) to other LDS buffer + outh (bf16)
    {
      unsigned char* fw = hfrag0 + (p ^ 1) * 4096;
#pragma unroll
      for (int jf = 0; jf < 2; ++jf)
#pragma unroll
        for (int r = 0; r < 4; ++r) {
          float iv = acc[0][jf][r], fv = acc[1][jf][r];
          float gv = acc[2][jf][r], ov = acc[3][jf][r];
          float cn = sigf(fv) * cst[jf][r] + sigf(iv) * tanh_(gv);
          cst[jf][r] = cn;
          float hv = sigf(ov) * tanh_(cn);
          outh[obase + (size_t)r * 131072 + (size_t)t * 512 + jf * 16] = f2b(hv);
          unsigned int b8 = __builtin_amdgcn_cvt_pk_fp8_f32(hv, hv, 0u, false) & 0xffu;
          fw[(v * 64 + jf * 32 + (l16 >> 3) * 16 + g * 4 + r) * 8 + (l16 & 7)] =
              (unsigned char)b8;
        }
    }
    __syncthreads();
  }
}

// ---------------- emission: [32768][33] f32 = outh @ Wcls^T + bcls ----------------
__global__ __launch_bounds__(256) void emis_k(const u16* __restrict__ outh,
    const u16* __restrict__ WclsP, const float* __restrict__ bcls,
    float* __restrict__ emiB) {
  int tid = threadIdx.x;
  int w = tid >> 6, lane = tid & 63, l16 = lane & 15, g = lane >> 4;
  int mrow = blockIdx.x * 64 + w * 16;
  f32x4 zero4 = {0.f, 0.f, 0.f, 0.f};
  f32x4 acc[3] = {zero4, zero4, zero4};
#pragma unroll
  for (int kf = 0; kf < 16; ++kf) {
    bf16x8 a = *(const bf16x8*)(outh + (size_t)(mrow + l16) * 512 + kf * 32 + g * 8);
#pragma unroll
    for (int nf = 0; nf < 3; ++nf) {
      bf16x8 bb = *(const bf16x8*)(WclsP + (size_t)(nf * 16 + l16) * 512 + kf * 32 + g * 8);
      acc[nf] = MFMA(a, bb, acc[nf]);
    }
  }
#pragma unroll
  for (int nf = 0; nf < 3; ++nf) {
    int c = nf * 16 + l16;
    if (c < 33) {
      float bc = bcls[c];
#pragma unroll
      for (int r = 0; r < 4; ++r)
        emiB[(size_t)(mrow + g * 4 + r) * 33 + c] = acc[nf][r] + bc;
    }
  }
}

// ---------------- golden path score per batch row ----------------
__global__ __launch_bounds__(256) void golden_k(const int* __restrict__ tag,
    const float* __restrict__ emiB, const float* __restrict__ T,
    float* __restrict__ gpart) {
  int b = blockIdx.x, l = threadIdx.x;
  int tg = tag[b * 256 + l];
  float val = 0.f;
  if (tg != 0) {
    int prev = (l == 0) ? 31 : tag[b * 256 + l - 1];
    val = emiB[(size_t)(b * 256 + l) * 33 + tg] + T[prev * 33 + tg];
  }
#pragma unroll
  for (int o = 32; o > 0; o >>= 1) val += __shfl_down(val, o);
  __shared__ float red[4];
  if ((threadIdx.x & 63) == 0) red[threadIdx.x >> 6] = val;
  __syncthreads();
  if (threadIdx.x == 0) gpart[b] = red[0] + red[1] + red[2] + red[3];
}

// ---------------- CRF forward (logsumexp scan), 1 wave per batch row ----------------
__global__ __launch_bounds__(64) void crf_k(const int* __restrict__ tag,
    const float* __restrict__ emiB, const float* __restrict__ T,
    float* __restrict__ endsc) {
  int b = blockIdx.x;
  int lane = threadIdx.x;
  __shared__ float Ts[1089];
  __shared__ float sc[33];
  for (int i = lane; i < 1089; i += 64) Ts[i] = T[i];
  int cnt = 0;
  for (int i = lane; i < 256; i += 64) cnt += (tag[b * 256 + i] != 0) ? 1 : 0;
#pragma unroll
  for (int o = 1; o < 64; o <<= 1) cnt += __shfl_xor(cnt, o);
  int len = cnt;
  __syncthreads();
  int c = lane;
  float tcol[33];
  if (c < 33) {
#pragma unroll
    for (int p = 0; p < 33; ++p) tcol[p] = Ts[p * 33 + c];
    sc[c] = emiB[(size_t)(b * 256) * 33 + c] + tcol[31];   // START=31
  }
  __syncthreads();
#pragma unroll 1
  for (int t = 1; t < 256; ++t) {
    if (t >= len) break;
    float nv = 0.f;
    if (c < 33) {
      float ec = emiB[(size_t)(b * 256 + t) * 33 + c];
      float vb[33];
      float mx = -3.0e38f;
#pragma unroll
      for (int p = 0; p < 33; ++p) { vb[p] = sc[p] + tcol[p]; mx = fmaxf(mx, vb[p]); }
      float s = 0.f;
#pragma unroll
      for (int p = 0; p < 33; ++p) s += __expf(vb[p] - mx);
      nv = ec + mx + __logf(s);
    }
    __syncthreads();
    if (c < 33) sc[c] = nv;
    __syncthreads();
  }
  if (lane == 0) endsc[b] = sc[32];   // END=32
}

// ---------------- finalize ----------------
__global__ __launch_bounds__(64) void fin_k(const float* __restrict__ gpart,
    const float* __restrict__ endsc, float* __restrict__ out) {
  int l = threadIdx.x;
  float v = (endsc[l] - gpart[l]) + (endsc[l + 64] - gpart[l + 64]);
#pragma unroll
  for (int o = 32; o > 0; o >>= 1) v += __shfl_down(v, o);
  if (l == 0) out[0] = v / 128.f;
}

extern "C" void kernel_launch(void* const* d_in, const int* in_sizes, int n_in,
                              void* d_out, int out_size, void* d_ws, size_t ws_size,
                              hipStream_t stream) {
  const int*   batch_data   = (const int*)d_in[0];
  const int*   batch_onerad = (const int*)d_in[1];
  const int*   batch_tag    = (const int*)d_in[2];
  const float* embed        = (const float*)d_in[3];
  const float* rad_embed    = (const float*)d_in[4];
  const float* Wih_f = (const float*)d_in[5];
  const float* Whh_f = (const float*)d_in[6];
  const float* bih_f = (const float*)d_in[7];
  const float* bhh_f = (const float*)d_in[8];
  const float* Wih_b = (const float*)d_in[9];
  const float* Whh_b = (const float*)d_in[10];
  const float* bih_b = (const float*)d_in[11];
  const float* bhh_b = (const float*)d_in[12];
  const float* Wcls  = (const float*)d_in[13];
  const float* bcls  = (const float*)d_in[14];
  const float* trans = (const float*)d_in[15];

  // workspace layout (~203.9 MB)
  char* ws = (char*)d_ws;
  u16*   Apack = (u16*)  (ws + 0);            // 29360128
  u16*   xg    = (u16*)  (ws + 29360128);     // 134217728
  u16*   WihP  = (u16*)  (ws + 163577856);    // 1835008
  unsigned int* WhhF8 = (unsigned int*)(ws + 165412864); // 524288
  float* biasP = (float*)(ws + 165937152);    // 8192
  u16*   WclsP = (u16*)  (ws + 165945344);    // 49152
  u16*   outh  = (u16*)  (ws + 165994496);    // 33554432
  float* emiB  = (float*)(ws + 199548928);    // 4325376
  float* gpart = (float*)(ws + 203874304);    // 512
  float* endsc = (float*)(ws + 203874816);    // 512

  pack_weights<<<4200, 256, 0, stream>>>(Wih_f, Wih_b, Whh_f, Whh_b, bih_f, bhh_f,
                                         bih_b, bhh_b, Wcls, WihP, WhhF8, biasP, WclsP);
  pack_A<<<14336, 256, 0, stream>>>(batch_data, batch_onerad, embed, rad_embed, Apack);
  gemm_xg<<<4096, 256, 0, stream>>>(Apack, WihP, biasP, xg);
  lstm_recur<<<16, 512, 139264, stream>>>(xg, (const unsigned char*)WhhF8, outh);
  emis_k<<<512, 256, 0, stream>>>(outh, WclsP, bcls, emiB);
  golden_k<<<128, 256, 0, stream>>>(batch_tag, emiB, trans, gpart);
  crf_k<<<128, 64, 0, stream>>>(batch_tag, emiB, trans, endsc);
  fin_k<<<1, 64, 0, stream>>>(gpart, endsc, (float*)d_out);
}

// Round 4
// 826.581 us; speedup vs baseline: 1.1339x; 1.1339x over previous
//
#include <hip/hip_runtime.h>
#include <hip/hip_bf16.h>
#include <stdint.h>

// LSTM-CRF forward loss. B=128 L=256 V=6000 E=128 RV=300 RD=100 H=256 C=33
// DIN=428 (pad to 448). Pipeline:
//   pack_weights (Wih bf16, Whh fp8-frag, bias, Wcls) -> pack_A -> gemm_xg
//   -> lstm_recur (16 wg; Whh PINNED in 128 VGPR/lane via volatile asm loads;
//      h fp8 LDS dbuf) -> emis_k -> golden_k -> crf_k -> fin_k

typedef unsigned short u16;
typedef __attribute__((ext_vector_type(8))) __bf16 bf16x8;
typedef __attribute__((ext_vector_type(4))) float f32x4;

struct __align__(8) u16x4 { u16 x, y, z, w; };

typedef const void __attribute__((address_space(1))) gas_t;
typedef void __attribute__((address_space(3))) las_t;

static __device__ __forceinline__ void gload16(const void* g, void* l) {
  __builtin_amdgcn_global_load_lds((gas_t*)g, (las_t*)l, 16, 0, 0);
}

static __device__ __forceinline__ u16 f2b(float x) {
  uint32_t u = __builtin_bit_cast(uint32_t, x);
  uint32_t r = u + 0x7fffu + ((u >> 16) & 1u);
  return (u16)(r >> 16);
}
static __device__ __forceinline__ float b2f(u16 u) {
  return __builtin_bit_cast(float, ((uint32_t)u) << 16);
}
static __device__ __forceinline__ float b2fu(unsigned int u) {
  return __builtin_bit_cast(float, u << 16);
}
static __device__ __forceinline__ float sigf(float x) {
  return __builtin_amdgcn_rcpf(1.f + __expf(-x));
}
static __device__ __forceinline__ float tanh_(float x) {
  return 1.f - 2.f * __builtin_amdgcn_rcpf(1.f + __expf(2.f * x));
}
static __device__ __forceinline__ f32x4 MFMA(bf16x8 a, bf16x8 b, f32x4 c) {
  return __builtin_amdgcn_mfma_f32_16x16x32_bf16(a, b, c, 0, 0, 0);
}

// ---------------- pack weights ----------------
// WihP[2048][448] bf16; bias[2048] f32 = bih+bhh; WclsP[48][512] bf16;
// WhhF8: fp8 e4m3 B-fragments, long-index ((d*8+v)*64 + (gate*2+jf)*8+kf)*64 + lane,
//   byte e: source Whh_d[row = gate*256+v*32+jf*16+(lane&15)][k = kf*32+(lane>>4)*8+e]
__global__ __launch_bounds__(256) void pack_weights(
    const float* __restrict__ Wih_f, const float* __restrict__ Wih_b,
    const float* __restrict__ Whh_f, const float* __restrict__ Whh_b,
    const float* __restrict__ bih_f, const float* __restrict__ bhh_f,
    const float* __restrict__ bih_b, const float* __restrict__ bhh_b,
    const float* __restrict__ Wcls,
    u16* __restrict__ WihP, unsigned int* __restrict__ WhhF8,
    float* __restrict__ biasP, u16* __restrict__ WclsP) {
  int idx = blockIdx.x * 256 + threadIdx.x;
  if (idx < 917504) {                       // 2*1024*448
    int d = idx / 458752;
    int rem = idx - d * 458752;
    int r = rem / 448, k = rem - r * 448;
    const float* W = d ? Wih_b : Wih_f;
    WihP[idx] = (k < 428) ? f2b(W[r * 428 + k]) : (u16)0;
  } else if (idx < 919552) {                // bias 2048
    int j = idx - 917504;
    int r = j & 1023;
    biasP[j] = (j >> 10) ? (bih_b[r] + bhh_b[r]) : (bih_f[r] + bhh_f[r]);
  } else if (idx < 944128) {                // Wcls 48*512
    int j = idx - 919552;
    int r = j >> 9, k = j & 511;
    WclsP[j] = (r < 33) ? f2b(Wcls[r * 512 + k]) : (u16)0;
  } else if (idx < 1075200) {               // WhhF8: 131072 dwords
    int q = idx - 944128;
    int eh = q & 1, li = (q >> 1) & 63, fi = (q >> 7) & 63;
    int v = (q >> 13) & 7, dd = q >> 16;
    int l16 = li & 15, g = li >> 4;
    int kf = fi & 7, gj = fi >> 3;
    int gate = gj >> 1, jf = gj & 1;
    int row = gate * 256 + v * 32 + jf * 16 + l16;
    int col = kf * 32 + g * 8 + eh * 4;
    const float* W = dd ? Whh_b : Whh_f;
    float4 f = *(const float4*)(W + (size_t)row * 256 + col);
    unsigned int r01 = __builtin_amdgcn_cvt_pk_fp8_f32(f.x, f.y, 0u, false) & 0xffffu;
    unsigned int r23 = __builtin_amdgcn_cvt_pk_fp8_f32(f.z, f.w, 0u, false) & 0xffffu;
    WhhF8[q] = r01 | (r23 << 16);
  }
}

// ---------------- gather + pack A: [32768][448] bf16 ----------------
__global__ __launch_bounds__(256) void pack_A(const int* __restrict__ data,
    const int* __restrict__ onerad, const float* __restrict__ embed,
    const float* __restrict__ rad, u16* __restrict__ A) {
  int idx = blockIdx.x * 256 + threadIdx.x;
  int m = idx / 112;
  int c = idx - m * 112;
  int k0 = c * 4;
  float4 vv;
  if (k0 < 128)      vv = *(const float4*)(embed + (size_t)data[m] * 128 + k0);
  else if (k0 < 228) vv = *(const float4*)(rad + (size_t)onerad[m] * 100 + (k0 - 128));
  else if (k0 < 328) vv = *(const float4*)(rad + (size_t)onerad[32768 + m] * 100 + (k0 - 228));
  else if (k0 < 428) vv = *(const float4*)(rad + (size_t)onerad[65536 + m] * 100 + (k0 - 328));
  else               vv = make_float4(0.f, 0.f, 0.f, 0.f);
  u16x4 o4 = { f2b(vv.x), f2b(vv.y), f2b(vv.z), f2b(vv.w) };
  *(u16x4*)(A + (size_t)m * 448 + k0) = o4;
}

// ---------------- xg GEMM: C[32768][2048] bf16 = A @ Wih^T + bias ----------------
__global__ __launch_bounds__(256) void gemm_xg(const u16* __restrict__ A,
    const u16* __restrict__ Bw, const float* __restrict__ bias,
    u16* __restrict__ Cout) {
  __shared__ u16 As[4096];
  __shared__ u16 Bs[4096];
  int bid = blockIdx.x;
  int mt = bid >> 4, nt = bid & 15;
  int m0 = mt * 128, n0 = nt * 128;
  int tid = threadIdx.x;
  int w = tid >> 6, lane = tid & 63, l16 = lane & 15, g = lane >> 4;
  int wr = w >> 1, wc = w & 1;
  int srow = tid >> 2, sch = tid & 3;
  f32x4 zero4 = {0.f, 0.f, 0.f, 0.f};
  f32x4 acc[4][4];
#pragma unroll
  for (int i = 0; i < 4; ++i)
#pragma unroll
    for (int j = 0; j < 4; ++j) acc[i][j] = zero4;
  for (int kk = 0; kk < 14; ++kk) {
    int kb = kk * 32;
    gload16(A + (size_t)(m0 + srow) * 448 + kb + sch * 8, (char*)As + tid * 16);
    gload16(A + (size_t)(m0 + srow + 64) * 448 + kb + sch * 8, (char*)As + 4096 + tid * 16);
    gload16(Bw + (size_t)(n0 + srow) * 448 + kb + sch * 8, (char*)Bs + tid * 16);
    gload16(Bw + (size_t)(n0 + srow + 64) * 448 + kb + sch * 8, (char*)Bs + 4096 + tid * 16);
    __syncthreads();
    bf16x8 af[4], bfr[4];
#pragma unroll
    for (int i = 0; i < 4; ++i) {
      af[i]  = *(const bf16x8*)((const char*)As + (wr * 64 + i * 16 + l16) * 64 + g * 16);
      bfr[i] = *(const bf16x8*)((const char*)Bs + (wc * 64 + i * 16 + l16) * 64 + g * 16);
    }
#pragma unroll
    for (int i = 0; i < 4; ++i)
#pragma unroll
      for (int j = 0; j < 4; ++j)
        acc[i][j] = MFMA(af[i], bfr[j], acc[i][j]);
    __syncthreads();
  }
  float bv[4];
#pragma unroll
  for (int j = 0; j < 4; ++j) bv[j] = bias[n0 + wc * 64 + j * 16 + l16];
#pragma unroll
  for (int i = 0; i < 4; ++i)
#pragma unroll
    for (int j = 0; j < 4; ++j) {
      int col = n0 + wc * 64 + j * 16 + l16;
#pragma unroll
      for (int r = 0; r < 4; ++r) {
        int row = m0 + wr * 64 + i * 16 + g * 4 + r;
        Cout[(size_t)row * 2048 + col] = f2b(acc[i][j][r] + bv[j]);
      }
    }
}

// ---------------- LSTM recurrence, Whh PINNED in registers ----------------
// 16 blocks x 512 thr. Wave v owns gate-cols {gate*256 + v*32 + [0,32)}.
// breg[64] = full per-wave Whh slice (fp8, 512B/lane = 128 VGPR), loaded via
// volatile asm global_load_dwordx2 -> compiler cannot sink/remat them, forced
// resident. h_{t-1} fp8 A-frags in LDS (4KB) double-buffered, ONE barrier/step.
// xg register-prefetched one step ahead.
__global__ __launch_bounds__(512, 2) void lstm_recur(const u16* __restrict__ xg,
    const unsigned char* __restrict__ WhhF8, u16* __restrict__ outh) {
  __shared__ unsigned char hfrag[2][4096];
  int blk = blockIdx.x;
  int d = blk >> 3, ch = blk & 7, b0 = ch * 16;
  int tid = threadIdx.x;
  int v = tid >> 6, lane = tid & 63, l16 = lane & 15, g = lane >> 4;

  // Pin all 64 B-fragments (gj 0..7 x kf 0..7) in VGPRs.
  const char* wbase = (const char*)WhhF8 + ((size_t)(d * 8 + v) * 4096 + lane) * 8;
  long breg[64];
#pragma unroll
  for (int i = 0; i < 64; ++i) {
    const char* p = wbase + i * 512;   // i = gj*8 + kf
    asm volatile("global_load_dwordx2 %0, %1, off" : "=v"(breg[i]) : "v"(p));
  }
  for (int i = tid; i < 2048; i += 512) ((int*)hfrag)[i] = 0;

  // xg prefetch pointers: 4 batch rows, 8 values each via imm offsets
  int t0 = d ? 255 : 0;
  const u16* xr0 = xg + (size_t)((b0 + g * 4 + 0) * 256 + t0) * 2048 + d * 1024 + v * 32 + l16;
  const u16* xr1 = xg + (size_t)((b0 + g * 4 + 1) * 256 + t0) * 2048 + d * 1024 + v * 32 + l16;
  const u16* xr2 = xg + (size_t)((b0 + g * 4 + 2) * 256 + t0) * 2048 + d * 1024 + v * 32 + l16;
  const u16* xr3 = xg + (size_t)((b0 + g * 4 + 3) * 256 + t0) * 2048 + d * 1024 + v * 32 + l16;
  int tstep = d ? -2048 : 2048;

  unsigned int px[32];
#pragma unroll
  for (int gate = 0; gate < 4; ++gate)
#pragma unroll
    for (int jf = 0; jf < 2; ++jf) {
      px[0 * 8 + gate * 2 + jf] = xr0[gate * 256 + jf * 16];
      px[1 * 8 + gate * 2 + jf] = xr1[gate * 256 + jf * 16];
      px[2 * 8 + gate * 2 + jf] = xr2[gate * 256 + jf * 16];
      px[3 * 8 + gate * 2 + jf] = xr3[gate * 256 + jf * 16];
    }

  asm volatile("s_waitcnt vmcnt(0)" ::: "memory");   // breg + px resident

  f32x4 zero4 = {0.f, 0.f, 0.f, 0.f};
  f32x4 cst[2] = {zero4, zero4};
  size_t obase = (size_t)((b0 + g * 4) * 256) * 512 + d * 256 + v * 32 + l16;
  __syncthreads();

#pragma unroll 1
  for (int tt = 0; tt < 256; ++tt) {
    int t = d ? (255 - tt) : tt;
    int p = tt & 1;
    // 1. acc init = xg (bias folded)
    f32x4 acc[4][2];
#pragma unroll
    for (int gate = 0; gate < 4; ++gate)
#pragma unroll
      for (int jf = 0; jf < 2; ++jf)
#pragma unroll
        for (int r = 0; r < 4; ++r)
          acc[gate][jf][r] = b2fu(px[r * 8 + gate * 2 + jf]);
    // 2. prefetch next step (benign in-workspace OOB at the final step)
    xr0 += tstep; xr1 += tstep; xr2 += tstep; xr3 += tstep;
#pragma unroll
    for (int gate = 0; gate < 4; ++gate)
#pragma unroll
      for (int jf = 0; jf < 2; ++jf) {
        px[0 * 8 + gate * 2 + jf] = xr0[gate * 256 + jf * 16];
        px[1 * 8 + gate * 2 + jf] = xr1[gate * 256 + jf * 16];
        px[2 * 8 + gate * 2 + jf] = xr2[gate * 256 + jf * 16];
        px[3 * 8 + gate * 2 + jf] = xr3[gate * 256 + jf * 16];
      }
    // 3. gates += h_{t-1} @ Whh^T  (fp8 MFMA; A preloaded from LDS, B pinned)
    {
      const long* fr = (const long*)(&hfrag[p][0]);
      long afr[8];
#pragma unroll
      for (int kf = 0; kf < 8; ++kf) afr[kf] = fr[kf * 64 + lane];
#pragma unroll
      for (int kf = 0; kf < 8; ++kf)
#pragma unroll
        for (int gj = 0; gj < 8; ++gj)
          acc[gj >> 1][gj & 1] = __builtin_amdgcn_mfma_f32_16x16x32_fp8_fp8(
              afr[kf], breg[gj * 8 + kf], acc[gj >> 1][gj & 1], 0, 0, 0);
    }
    // 4. activations; write h (fp8) to other LDS buffer + outh (bf16)
    {
      unsigned char* fw = &hfrag[p ^ 1][0];
#pragma unroll
      for (int jf = 0; jf < 2; ++jf)
#pragma unroll
        for (int r = 0; r < 4; ++r) {
          float iv = acc[0][jf][r], fv = acc[1][jf][r];
          float gv = acc[2][jf][r], ov = acc[3][jf][r];
          float cn = sigf(fv) * cst[jf][r] + sigf(iv) * tanh_(gv);
          cst[jf][r] = cn;
          float hv = sigf(ov) * tanh_(cn);
          outh[obase + (size_t)r * 131072 + (size_t)t * 512 + jf * 16] = f2b(hv);
          unsigned int b8 = __builtin_amdgcn_cvt_pk_fp8_f32(hv, hv, 0u, false) & 0xffu;
          fw[(v * 64 + jf * 32 + (l16 >> 3) * 16 + g * 4 + r) * 8 + (l16 & 7)] =
              (unsigned char)b8;
        }
    }
    __syncthreads();
  }
}

// ---------------- emission: [32768][33] f32 = outh @ Wcls^T + bcls ----------------
__global__ __launch_bounds__(256) void emis_k(const u16* __restrict__ outh,
    const u16* __restrict__ WclsP, const float* __restrict__ bcls,
    float* __restrict__ emiB) {
  int tid = threadIdx.x;
  int w = tid >> 6, lane = tid & 63, l16 = lane & 15, g = lane >> 4;
  int mrow = blockIdx.x * 64 + w * 16;
  f32x4 zero4 = {0.f, 0.f, 0.f, 0.f};
  f32x4 acc[3] = {zero4, zero4, zero4};
#pragma unroll
  for (int kf = 0; kf < 16; ++kf) {
    bf16x8 a = *(const bf16x8*)(outh + (size_t)(mrow + l16) * 512 + kf * 32 + g * 8);
#pragma unroll
    for (int nf = 0; nf < 3; ++nf) {
      bf16x8 bb = *(const bf16x8*)(WclsP + (size_t)(nf * 16 + l16) * 512 + kf * 32 + g * 8);
      acc[nf] = MFMA(a, bb, acc[nf]);
    }
  }
#pragma unroll
  for (int nf = 0; nf < 3; ++nf) {
    int c = nf * 16 + l16;
    if (c < 33) {
      float bc = bcls[c];
#pragma unroll
      for (int r = 0; r < 4; ++r)
        emiB[(size_t)(mrow + g * 4 + r) * 33 + c] = acc[nf][r] + bc;
    }
  }
}

// ---------------- golden path score per batch row ----------------
__global__ __launch_bounds__(256) void golden_k(const int* __restrict__ tag,
    const float* __restrict__ emiB, const float* __restrict__ T,
    float* __restrict__ gpart) {
  int b = blockIdx.x, l = threadIdx.x;
  int tg = tag[b * 256 + l];
  float val = 0.f;
  if (tg != 0) {
    int prev = (l == 0) ? 31 : tag[b * 256 + l - 1];
    val = emiB[(size_t)(b * 256 + l) * 33 + tg] + T[prev * 33 + tg];
  }
#pragma unroll
  for (int o = 32; o > 0; o >>= 1) val += __shfl_down(val, o);
  __shared__ float red[4];
  if ((threadIdx.x & 63) == 0) red[threadIdx.x >> 6] = val;
  __syncthreads();
  if (threadIdx.x == 0) gpart[b] = red[0] + red[1] + red[2] + red[3];
}

// ---------------- CRF forward (logsumexp scan), 1 wave per batch row ----------------
__global__ __launch_bounds__(64) void crf_k(const int* __restrict__ tag,
    const float* __restrict__ emiB, const float* __restrict__ T,
    float* __restrict__ endsc) {
  int b = blockIdx.x;
  int lane = threadIdx.x;
  __shared__ float Ts[1089];
  __shared__ float sc[33];
  for (int i = lane; i < 1089; i += 64) Ts[i] = T[i];
  int cnt = 0;
  for (int i = lane; i < 256; i += 64) cnt += (tag[b * 256 + i] != 0) ? 1 : 0;
#pragma unroll
  for (int o = 1; o < 64; o <<= 1) cnt += __shfl_xor(cnt, o);
  int len = cnt;
  __syncthreads();
  int c = lane;
  float tcol[33];
  if (c < 33) {
#pragma unroll
    for (int p = 0; p < 33; ++p) tcol[p] = Ts[p * 33 + c];
    sc[c] = emiB[(size_t)(b * 256) * 33 + c] + tcol[31];   // START=31
  }
  __syncthreads();
#pragma unroll 1
  for (int t = 1; t < 256; ++t) {
    if (t >= len) break;
    float nv = 0.f;
    if (c < 33) {
      float ec = emiB[(size_t)(b * 256 + t) * 33 + c];
      float vb[33];
      float mx = -3.0e38f;
#pragma unroll
      for (int p = 0; p < 33; ++p) { vb[p] = sc[p] + tcol[p]; mx = fmaxf(mx, vb[p]); }
      float s = 0.f;
#pragma unroll
      for (int p = 0; p < 33; ++p) s += __expf(vb[p] - mx);
      nv = ec + mx + __logf(s);
    }
    __syncthreads();
    if (c < 33) sc[c] = nv;
    __syncthreads();
  }
  if (lane == 0) endsc[b] = sc[32];   // END=32
}

// ---------------- finalize ----------------
__global__ __launch_bounds__(64) void fin_k(const float* __restrict__ gpart,
    const float* __restrict__ endsc, float* __restrict__ out) {
  int l = threadIdx.x;
  float v = (endsc[l] - gpart[l]) + (endsc[l + 64] - gpart[l + 64]);
#pragma unroll
  for (int o = 32; o > 0; o >>= 1) v += __shfl_down(v, o);
  if (l == 0) out[0] = v / 128.f;
}

extern "C" void kernel_launch(void* const* d_in, const int* in_sizes, int n_in,
                              void* d_out, int out_size, void* d_ws, size_t ws_size,
                              hipStream_t stream) {
  const int*   batch_data   = (const int*)d_in[0];
  const int*   batch_onerad = (const int*)d_in[1];
  const int*   batch_tag    = (const int*)d_in[2];
  const float* embed        = (const float*)d_in[3];
  const float* rad_embed    = (const float*)d_in[4];
  const float* Wih_f = (const float*)d_in[5];
  const float* Whh_f = (const float*)d_in[6];
  const float* bih_f = (const float*)d_in[7];
  const float* bhh_f = (const float*)d_in[8];
  const float* Wih_b = (const float*)d_in[9];
  const float* Whh_b = (const float*)d_in[10];
  const float* bih_b = (const float*)d_in[11];
  const float* bhh_b = (const float*)d_in[12];
  const float* Wcls  = (const float*)d_in[13];
  const float* bcls  = (const float*)d_in[14];
  const float* trans = (const float*)d_in[15];

  // workspace layout (~203.9 MB)
  char* ws = (char*)d_ws;
  u16*   Apack = (u16*)  (ws + 0);            // 29360128
  u16*   xg    = (u16*)  (ws + 29360128);     // 134217728
  u16*   WihP  = (u16*)  (ws + 163577856);    // 1835008
  unsigned int* WhhF8 = (unsigned int*)(ws + 165412864); // 524288
  float* biasP = (float*)(ws + 165937152);    // 8192
  u16*   WclsP = (u16*)  (ws + 165945344);    // 49152
  u16*   outh  = (u16*)  (ws + 165994496);    // 33554432
  float* emiB  = (float*)(ws + 199548928);    // 4325376
  float* gpart = (float*)(ws + 203874304);    // 512
  float* endsc = (float*)(ws + 203874816);    // 512

  pack_weights<<<4200, 256, 0, stream>>>(Wih_f, Wih_b, Whh_f, Whh_b, bih_f, bhh_f,
                                         bih_b, bhh_b, Wcls, WihP, WhhF8, biasP, WclsP);
  pack_A<<<14336, 256, 0, stream>>>(batch_data, batch_onerad, embed, rad_embed, Apack);
  gemm_xg<<<4096, 256, 0, stream>>>(Apack, WihP, biasP, xg);
  lstm_recur<<<16, 512, 0, stream>>>(xg, (const unsigned char*)WhhF8, outh);
  emis_k<<<512, 256, 0, stream>>>(outh, WclsP, bcls, emiB);
  golden_k<<<128, 256, 0, stream>>>(batch_tag, emiB, trans, gpart);
  crf_k<<<128, 64, 0, stream>>>(batch_tag, emiB, trans, endsc);
  fin_k<<<1, 64, 0, stream>>>(gpart, endsc, (float*)d_out);
}